// Round 7
// baseline (695.603 us; speedup 1.0000x reference)
//
#include <hip/hip_runtime.h>
#include <math.h>

#define NTOK 4096   // B*T tokens
#define DIM  1024
#define HID  4096
#define NEXP 8
#define NROW 8192   // NTOK * K (top-2): every token occupies exactly 2 rows
#define KSPLIT 2    // non-atomic split-K for gemm2: separate ybuf slices, summed in combine
#define MAXTILE 71  // max Σ_e ceil(cnt_e/128) given Σcnt=8192, 8 experts

typedef __bf16 bf16;
typedef __attribute__((ext_vector_type(8))) __bf16 bf16x8;
typedef __attribute__((ext_vector_type(4))) float floatx4;

// async global->LDS, 16B per lane. LDS dest is wave-uniform base + lane*16.
__device__ __forceinline__ void gl_lds16(const bf16* g, bf16* l) {
    __builtin_amdgcn_global_load_lds(
        (const __attribute__((address_space(1))) void*)g,
        (__attribute__((address_space(3))) void*)l, 16, 0, 0);
}

// bijective XCD swizzle (m204): consecutive logical ids land on the same XCD chunk.
// requires nwg % 8 == 0 (both GEMM grids are).
__device__ __forceinline__ int xcd_swz(int orig, int nwg) {
    int q = nwg >> 3;
    return (orig & 7) * q + (orig >> 3);
}

// branchless GELU: 0.5v(1+erf(v/sqrt2)), erf via A&S 7.1.26 (|eps|<=1.5e-7 abs).
__device__ __forceinline__ float gelu_f(float v) {
    float x  = v * 0.70710678118654752f;
    float ax = fabsf(x);
    float t  = __builtin_amdgcn_rcpf(fmaf(0.3275911f, ax, 1.0f));
    float p  = fmaf(fmaf(fmaf(fmaf(1.061405429f, t, -1.453152027f),
                              t, 1.421413741f),
                         t, -0.284496736f),
                    t, 0.254829592f);
    p *= t;
    float ex = __expf(-x * x);
    float er = fmaf(-p, ex, 1.0f);
    er = copysignf(er, v);
    return 0.5f * v * (1.0f + er);
}

__global__ void zero_k(int* __restrict__ p) {
    if (threadIdx.x < 16) p[threadIdx.x] = 0;   // counts[8] + counts2[8]
}

// ---------------- router (+ fused x->bf16 conversion): one wave per token ----------------
__global__ __launch_bounds__(256) void router_k(
    const float* __restrict__ x, const float* __restrict__ gw, const float* __restrict__ gb,
    int* __restrict__ counts, int* __restrict__ tok_e, float* __restrict__ tok_g,
    bf16* __restrict__ xb)
{
    __shared__ float gws[NEXP][DIM];   // 32 KB fp32, transposed
    int t = threadIdx.x;
#pragma unroll
    for (int i = 0; i < 32; ++i) {
        int g = i * 256 + t;                 // coalesced read of gw [DIM][NEXP]
        gws[g & 7][g >> 3] = gw[g];
    }
    __syncthreads();

    int gid = blockIdx.x * 256 + t;
    int wv = gid >> 6, lane = gid & 63;       // grid covers exactly NTOK waves
    const float* xr = x + (size_t)wv * DIM;
    bf16* xw = xb + (size_t)wv * DIM;
    float acc[NEXP];
#pragma unroll
    for (int e = 0; e < NEXP; ++e) acc[e] = 0.f;
#pragma unroll
    for (int j = 0; j < 16; ++j) {
        int d = lane + j * 64;               // lane-consecutive: coalesced + bank-conflict-free
        float xv = xr[d];
        xw[d] = (bf16)xv;                    // fused convx
#pragma unroll
        for (int e = 0; e < NEXP; ++e) acc[e] += xv * gws[e][d];
    }
#pragma unroll
    for (int off = 32; off > 0; off >>= 1) {
#pragma unroll
        for (int e = 0; e < NEXP; ++e) acc[e] += __shfl_xor(acc[e], off, 64);
    }
    if (lane == 0) {
        float lg[NEXP], m = -1e30f;
        for (int e = 0; e < NEXP; ++e) { lg[e] = acc[e] + gb[e]; m = fmaxf(m, lg[e]); }
        float p[NEXP], s = 0.f;
        for (int e = 0; e < NEXP; ++e) { p[e] = expf(lg[e] - m); s += p[e]; }
        int e0 = 0;
        for (int e = 1; e < NEXP; ++e) if (p[e] > p[e0]) e0 = e;  // strict > : first index wins ties
        int e1 = (e0 == 0) ? 1 : 0;
        for (int e = 0; e < NEXP; ++e) if (e != e0 && p[e] > p[e1]) e1 = e;
        float g0 = p[e0] / s, g1 = p[e1] / s;
        float gs = g0 + g1 + 1e-9f;
        g0 /= gs; g1 /= gs;
        tok_e[wv * 2] = e0; tok_e[wv * 2 + 1] = e1;
        tok_g[wv * 2] = g0; tok_g[wv * 2 + 1] = g1;
        atomicAdd(&counts[e0], 1);
        atomicAdd(&counts[e1], 1);
    }
}

// scan + flattened tile table: tile[i] = (expert, row-tile) for every REAL 128-row tile.
__global__ void scan_k(const int* __restrict__ counts, int* __restrict__ base,
                       int* __restrict__ tile_e, int* __restrict__ tile_rt,
                       int* __restrict__ ntile)
{
    if (threadIdx.x == 0) {
        int s = 0, nt = 0;
#pragma unroll
        for (int e = 0; e < NEXP; ++e) {
            base[e] = s;
            int c = counts[e];
            int nte = (c + 127) >> 7;
            for (int rt = 0; rt < nte; ++rt) { tile_e[nt] = e; tile_rt[nt] = rt; ++nt; }
            s += c;
        }
        base[NEXP] = s;
        ntile[0] = nt;
    }
}

__global__ __launch_bounds__(256) void scatter_k(
    const int* __restrict__ tok_e, const float* __restrict__ tok_g,
    const int* __restrict__ base, int* __restrict__ counts2,
    int* __restrict__ row_token, float* __restrict__ row_gate, int* __restrict__ tok_row)
{
    int tk = blockIdx.x * 256 + threadIdx.x;
    if (tk >= NTOK) return;
#pragma unroll
    for (int k = 0; k < 2; ++k) {
        int e = tok_e[tk * 2 + k];
        int slot = atomicAdd(&counts2[e], 1);
        int r = base[e] + slot;
        row_token[r] = tk;
        row_gate[r] = tok_g[tk * 2 + k];
        tok_row[tk * 2 + k] = r;
    }
}

// ---- batched tile transpose + fp32->bf16 conversion (unchanged) ----
__global__ __launch_bounds__(256) void transpose_k(
    const float* __restrict__ src, bf16* __restrict__ dst,
    int R, int sld, size_t soff, size_t es, size_t ed)
{
    int e = blockIdx.z;
    bf16* d = dst + (size_t)e * ed;
    __shared__ __align__(16) bf16 tile[64 * 64];
    int t = threadIdx.x;
    int r0 = blockIdx.y * 64, c0 = blockIdx.x * 64;
#pragma unroll
    for (int i = 0; i < 2; ++i) {
        int c = t + i * 256;
        int rr = c >> 3, cc = c & 7;
        size_t eo = soff + (size_t)e * es + (size_t)(r0 + rr) * sld + c0 + cc * 8;
        floatx4 a = *(const floatx4*)(src + eo);
        floatx4 b = *(const floatx4*)(src + eo + 4);
        bf16x8 v;
#pragma unroll
        for (int j = 0; j < 4; ++j) { v[j] = (bf16)a[j]; v[4 + j] = (bf16)b[j]; }
        *(bf16x8*)&tile[rr * 64 + ((cc ^ ((rr >> 3) & 7)) * 8)] = v;
    }
    __syncthreads();
#pragma unroll
    for (int i = 0; i < 2; ++i) {
        int c = t + i * 256;
        int oc = c >> 3;
        int occ = c & 7;
        bf16x8 v;
#pragma unroll
        for (int j = 0; j < 8; ++j) {
            int r = occ * 8 + j;
            int p = (oc >> 3) ^ ((r >> 3) & 7);
            v[j] = tile[r * 64 + p * 8 + (oc & 7)];
        }
        *(bf16x8*)&d[(size_t)(c0 + oc) * R + r0 + occ * 8] = v;
    }
}

// ---------------- GEMM1: h[:, chunk] = gelu(gather(xb) @ w1[e][:, chunk] + b1[e][chunk]) ------
// v7: 1-D grid over flattened tile table + XCD swizzle; 32 n-blocks of one tile adjacent
//     -> xb gather panel fetched once per XCD L2, not 8x.
__global__ __launch_bounds__(256) void gemm1_k(
    const bf16* __restrict__ xb, const bf16* __restrict__ w1t, const float* __restrict__ b1,
    const int* __restrict__ counts, const int* __restrict__ base,
    const int* __restrict__ tile_e, const int* __restrict__ tile_rt,
    const int* __restrict__ ntile,
    const int* __restrict__ row_token, bf16* __restrict__ hbuf, int Nc, int bias_off)
{
    const int lid = xcd_swz(blockIdx.x, gridDim.x);
    const int ty = lid >> 5, tx = lid & 31;        // Nc/128 == 32 when Hc==HID
    if (ty >= ntile[0]) return;
    const int e = tile_e[ty];
    const int rb = base[e] + tile_rt[ty] * 128;
    const int rend = base[e] + counts[e];
    const int n0 = tx * 128;

    __shared__ __align__(16) bf16 As[2][128 * 32];   // 2 x 8 KB
    __shared__ __align__(16) bf16 Bs[2][128 * 32];

    const int t = threadIdx.x;
    const int wv = t >> 6, lane = t & 63;
    const int s0 = t, s1 = t + 256;
    const int ar0 = s0 >> 2, ac0 = (s0 & 3) ^ ((s0 >> 3) & 3);
    const int ar1 = s1 >> 2, ac1 = (s1 & 3) ^ ((s1 >> 3) & 3);
    int rr0 = rb + ar0; if (rr0 > NROW - 1) rr0 = NROW - 1;   // clamp: padded rows read valid data
    int rr1 = rb + ar1; if (rr1 > NROW - 1) rr1 = NROW - 1;
    const bf16* ga0 = xb + (size_t)row_token[rr0] * DIM + ac0 * 8;
    const bf16* ga1 = xb + (size_t)row_token[rr1] * DIM + ac1 * 8;
    const bf16* wb = w1t + (size_t)e * Nc * DIM;
    const bf16* gb0 = wb + (size_t)(n0 + ar0) * DIM + ac0 * 8;
    const bf16* gb1 = wb + (size_t)(n0 + ar1) * DIM + ac1 * 8;
    const int off0 = wv * 512, off1 = 2048 + wv * 512;

    floatx4 acc[4][4];
#pragma unroll
    for (int i = 0; i < 4; ++i)
#pragma unroll
        for (int j = 0; j < 4; ++j) acc[i][j] = floatx4{0.f, 0.f, 0.f, 0.f};

    const int wr = (wv >> 1) * 64, wc = (wv & 1) * 64;
    const int lr = lane & 15;
    const int ck = lane >> 4;

    gl_lds16(ga0, &As[0][off0]); gl_lds16(ga1, &As[0][off1]);
    gl_lds16(gb0, &Bs[0][off0]); gl_lds16(gb1, &Bs[0][off1]);

    const int NSTEP = DIM / 32;   // 32
#pragma unroll 2
    for (int i = 0; i < NSTEP; ++i) {
        const int bc = i & 1;
        asm volatile("s_waitcnt vmcnt(0)" ::: "memory");
        __builtin_amdgcn_s_barrier();
        asm volatile("" ::: "memory");
        if (i + 1 < NSTEP) {
            const int kn = (i + 1) * 32;
            gl_lds16(ga0 + kn, &As[bc ^ 1][off0]); gl_lds16(ga1 + kn, &As[bc ^ 1][off1]);
            gl_lds16(gb0 + kn, &Bs[bc ^ 1][off0]); gl_lds16(gb1 + kn, &Bs[bc ^ 1][off1]);
        }
        bf16x8 af[4], bg[4];
#pragma unroll
        for (int q = 0; q < 4; ++q) {
            int r = wr + q * 16 + lr;
            af[q] = *(const bf16x8*)&As[bc][r * 32 + ((ck ^ ((r >> 1) & 3)) * 8)];
        }
#pragma unroll
        for (int q = 0; q < 4; ++q) {
            int r = wc + q * 16 + lr;
            bg[q] = *(const bf16x8*)&Bs[bc][r * 32 + ((ck ^ ((r >> 1) & 3)) * 8)];
        }
        __builtin_amdgcn_s_setprio(1);
#pragma unroll
        for (int mi = 0; mi < 4; ++mi)
#pragma unroll
            for (int ni = 0; ni < 4; ++ni)
                acc[mi][ni] = __builtin_amdgcn_mfma_f32_16x16x32_bf16(af[mi], bg[ni], acc[mi][ni], 0, 0, 0);
        __builtin_amdgcn_s_setprio(0);
    }

#pragma unroll
    for (int mi = 0; mi < 4; ++mi) {
#pragma unroll
        for (int r = 0; r < 4; ++r) {
            int m = wr + mi * 16 + (lane >> 4) * 4 + r;
            int gr = rb + m;
            if (gr < rend) {
#pragma unroll
                for (int ni = 0; ni < 4; ++ni) {
                    int col = n0 + wc + ni * 16 + lr;
                    float v = acc[mi][ni][r] + b1[e * HID + bias_off + col];
                    hbuf[(size_t)gr * Nc + col] = (bf16)gelu_f(v);
                }
            }
        }
    }
}

// ---------------- GEMM2 (split-K=2, non-atomic) ------------------------------------------
// v7: 1-D grid over tile table + XCD swizzle, ks-major ordering: the 8 n-blocks of one
//     (tile, k-half) are adjacent (hbuf panel fetched once per XCD); each XCD chunk stays
//     within one (expert, k-half) w2 slice for w2 L2 reuse.
__global__ __launch_bounds__(256) void gemm2_k(
    const bf16* __restrict__ hbuf, const bf16* __restrict__ w2t,
    const int* __restrict__ counts, const int* __restrict__ base,
    const int* __restrict__ tile_e, const int* __restrict__ tile_rt,
    const int* __restrict__ ntile,
    float* __restrict__ ybuf, int Kc, int first)
{
    const int lid = xcd_swz(blockIdx.x, gridDim.x);
    const int tx = lid & 7;
    const int tmp = lid >> 3;                 // 0 .. 2*MAXTILE-1
    const int ks = tmp / MAXTILE;
    const int ty = tmp - ks * MAXTILE;
    if (ty >= ntile[0]) return;
    const int e = tile_e[ty];
    const int rb = base[e] + tile_rt[ty] * 128;
    const int rend = base[e] + counts[e];
    const int n0 = tx * 128;
    const int klen = Kc / KSPLIT;
    const int kbeg = ks * klen;

    __shared__ __align__(16) bf16 As[3][128 * 32];   // 3 x 8 KB
    __shared__ __align__(16) bf16 Bs[3][128 * 32];

    const int t = threadIdx.x;
    const int wv = t >> 6, lane = t & 63;
    const int s0 = t, s1 = t + 256;
    const int ar0 = s0 >> 2, ac0 = (s0 & 3) ^ ((s0 >> 3) & 3);
    const int ar1 = s1 >> 2, ac1 = (s1 & 3) ^ ((s1 >> 3) & 3);
    int rr0 = rb + ar0; if (rr0 > NROW - 1) rr0 = NROW - 1;
    int rr1 = rb + ar1; if (rr1 > NROW - 1) rr1 = NROW - 1;
    const bf16* ga0 = hbuf + (size_t)rr0 * Kc + kbeg + ac0 * 8;
    const bf16* ga1 = hbuf + (size_t)rr1 * Kc + kbeg + ac1 * 8;
    const bf16* wb = w2t + (size_t)e * DIM * Kc;
    const bf16* gb0 = wb + (size_t)(n0 + ar0) * Kc + kbeg + ac0 * 8;
    const bf16* gb1 = wb + (size_t)(n0 + ar1) * Kc + kbeg + ac1 * 8;
    const int off0 = wv * 512, off1 = 2048 + wv * 512;

    floatx4 acc[4][4];
#pragma unroll
    for (int i = 0; i < 4; ++i)
#pragma unroll
        for (int j = 0; j < 4; ++j) acc[i][j] = floatx4{0.f, 0.f, 0.f, 0.f};

    const int wr = (wv >> 1) * 64, wc = (wv & 1) * 64;
    const int lr = lane & 15;
    const int ck = lane >> 4;

    gl_lds16(ga0,      &As[0][off0]); gl_lds16(ga1,      &As[0][off1]);
    gl_lds16(gb0,      &Bs[0][off0]); gl_lds16(gb1,      &Bs[0][off1]);
    gl_lds16(ga0 + 32, &As[1][off0]); gl_lds16(ga1 + 32, &As[1][off1]);
    gl_lds16(gb0 + 32, &Bs[1][off0]); gl_lds16(gb1 + 32, &Bs[1][off1]);

    const int nstep = klen >> 5;             // 64
    int bc = 0;
    for (int i = 0; i < nstep; ++i) {
        if (i + 1 < nstep) asm volatile("s_waitcnt vmcnt(4)" ::: "memory");
        else               asm volatile("s_waitcnt vmcnt(0)" ::: "memory");
        __builtin_amdgcn_s_barrier();
        asm volatile("" ::: "memory");
        if (i + 2 < nstep) {
            int bs = bc + 2; if (bs >= 3) bs -= 3;
            const int kn = (i + 2) * 32;
            gl_lds16(ga0 + kn, &As[bs][off0]); gl_lds16(ga1 + kn, &As[bs][off1]);
            gl_lds16(gb0 + kn, &Bs[bs][off0]); gl_lds16(gb1 + kn, &Bs[bs][off1]);
        }
        bf16x8 af[4], bg[4];
#pragma unroll
        for (int q = 0; q < 4; ++q) {
            int r = wr + q * 16 + lr;
            af[q] = *(const bf16x8*)&As[bc][r * 32 + ((ck ^ ((r >> 1) & 3)) * 8)];
        }
#pragma unroll
        for (int q = 0; q < 4; ++q) {
            int r = wc + q * 16 + lr;
            bg[q] = *(const bf16x8*)&Bs[bc][r * 32 + ((ck ^ ((r >> 1) & 3)) * 8)];
        }
        __builtin_amdgcn_s_setprio(1);
#pragma unroll
        for (int mi = 0; mi < 4; ++mi)
#pragma unroll
            for (int ni = 0; ni < 4; ++ni)
                acc[mi][ni] = __builtin_amdgcn_mfma_f32_16x16x32_bf16(af[mi], bg[ni], acc[mi][ni], 0, 0, 0);
        __builtin_amdgcn_s_setprio(0);
        bc += 1; if (bc >= 3) bc -= 3;
    }

    float* yb = ybuf + (size_t)ks * NROW * DIM;
#pragma unroll
    for (int mi = 0; mi < 4; ++mi) {
#pragma unroll
        for (int r = 0; r < 4; ++r) {
            int m = wr + mi * 16 + (lane >> 4) * 4 + r;
            int gr = rb + m;
            if (gr < rend) {
#pragma unroll
                for (int ni = 0; ni < 4; ++ni) {
                    int col = n0 + wc + ni * 16 + lr;
                    size_t idx = (size_t)gr * DIM + col;
                    float v = acc[mi][ni][r];
                    yb[idx] = first ? v : (yb[idx] + v);
                }
            }
        }
    }
}

// ---------------- combine: out[t] = Σ_k g_k * (y0[row_k] + y1[row_k] + b2[e_k]) --------------
__global__ __launch_bounds__(256) void combine_k(
    const float* __restrict__ ybuf, const int* __restrict__ tok_row,
    const int* __restrict__ tok_e, const float* __restrict__ tok_g,
    const float* __restrict__ b2, float* __restrict__ out)
{
    int i = blockIdx.x * 256 + threadIdx.x;
    int tk = i >> 8;
    int dc = (i & 255) * 4;
    int ra = tok_row[tk * 2], rbx = tok_row[tk * 2 + 1];
    int ea = tok_e[tk * 2],  eb = tok_e[tk * 2 + 1];
    float ga = tok_g[tk * 2], gbv = tok_g[tk * 2 + 1];
    const float* y0 = ybuf;
    const float* y1 = ybuf + (size_t)NROW * DIM;
    floatx4 a0 = *(const floatx4*)&y0[(size_t)ra * DIM + dc];
    floatx4 a1 = *(const floatx4*)&y1[(size_t)ra * DIM + dc];
    floatx4 b0 = *(const floatx4*)&y0[(size_t)rbx * DIM + dc];
    floatx4 b1v = *(const floatx4*)&y1[(size_t)rbx * DIM + dc];
    floatx4 b2a = *(const floatx4*)&b2[ea * DIM + dc];
    floatx4 b2b = *(const floatx4*)&b2[eb * DIM + dc];
    floatx4 o;
#pragma unroll
    for (int j = 0; j < 4; ++j)
        o[j] = ga * (a0[j] + a1[j] + b2a[j]) + gbv * (b0[j] + b1v[j] + b2b[j]);
    *(floatx4*)&out[(size_t)tk * DIM + dc] = o;
}

extern "C" void kernel_launch(void* const* d_in, const int* in_sizes, int n_in,
                              void* d_out, int out_size, void* d_ws, size_t ws_size,
                              hipStream_t stream)
{
    const float* x  = (const float*)d_in[0];
    const float* gw = (const float*)d_in[1];
    const float* gb = (const float*)d_in[2];
    const float* w1 = (const float*)d_in[3];
    const float* b1 = (const float*)d_in[4];
    const float* w2 = (const float*)d_in[5];
    const float* b2 = (const float*)d_in[6];
    float* out = (float*)d_out;

    char* w = (char*)d_ws;
    int*   counts  = (int*)(w + 0);        // 8 ints
    int*   counts2 = (int*)(w + 32);       // 8 ints
    int*   base    = (int*)(w + 64);       // 9 ints
    int*   ntile   = (int*)(w + 112);      // 1 int
    int*   tile_e  = (int*)(w + 128);      // 71 ints
    int*   tile_rt = (int*)(w + 512);      // 71 ints
    int*   tok_e   = (int*)(w + 1024);
    float* tok_g   = (float*)(w + 1024 + 32768);
    int*   row_tok = (int*)(w + 1024 + 2 * 32768);
    float* row_g   = (float*)(w + 1024 + 3 * 32768);
    int*   tok_row = (int*)(w + 1024 + 4 * 32768);
    size_t off = 1024 + 5 * 32768;                                      // 256-aligned
    bf16*  xb   = (bf16*)(w + off);   off += (size_t)NTOK * DIM * 2;    // 8 MiB
    float* ybuf = (float*)(w + off);  off += (size_t)KSPLIT * NROW * DIM * 4;  // 64 MiB

    // choose H-chunk so total footprint fits ws_size (deterministic across calls)
    int Hc = HID;
    for (;;) {
        size_t need = off + (size_t)NEXP * Hc * DIM * 2 + (size_t)NROW * Hc * 2;
        if (need <= ws_size || Hc == 128) break;
        Hc >>= 1;
    }
    bf16* wT   = (bf16*)(w + off);  off += (size_t)NEXP * Hc * DIM * 2;
    bf16* hbuf = (bf16*)(w + off);                                       // [NROW][Hc]

    zero_k<<<1, 64, 0, stream>>>(counts);
    router_k<<<NTOK / 4, 256, 0, stream>>>(x, gw, gb, counts, tok_e, tok_g, xb);
    scan_k<<<1, 64, 0, stream>>>(counts, base, tile_e, tile_rt, ntile);
    scatter_k<<<NTOK / 256, 256, 0, stream>>>(tok_e, tok_g, base, counts2, row_tok, row_g, tok_row);

    const int nc = HID / Hc;
    for (int ch = 0; ch < nc; ++ch) {
        transpose_k<<<dim3(Hc / 64, DIM / 64, NEXP), 256, 0, stream>>>(
            w1, wT, DIM, HID, (size_t)ch * Hc, (size_t)DIM * HID, (size_t)Hc * DIM);
        gemm1_k<<<MAXTILE * (Hc / 128), 256, 0, stream>>>(          // 71*32 = 2272 (%8==0)
            xb, wT, b1, counts, base, tile_e, tile_rt, ntile, row_tok, hbuf, Hc, ch * Hc);
        transpose_k<<<dim3(DIM / 64, Hc / 64, NEXP), 256, 0, stream>>>(
            w2, wT, Hc, DIM, (size_t)ch * Hc * DIM, (size_t)HID * DIM, (size_t)DIM * Hc);
        gemm2_k<<<MAXTILE * KSPLIT * (DIM / 128), 256, 0, stream>>>( // 71*16 = 1136 (%8==0)
            hbuf, wT, counts, base, tile_e, tile_rt, ntile, ybuf, Hc, ch == 0);
    }

    combine_k<<<NTOK, 256, 0, stream>>>(ybuf, tok_row, tok_e, tok_g, b2, out);
}